// Round 1
// baseline (1373.090 us; speedup 1.0000x reference)
//
#include <hip/hip_runtime.h>

// ---------- problem constants ----------
#define BATCH 2
#define SEQ   2048
#define HID   2048
#define NH    16
#define NKV   8
#define HD    128
#define M_ROWS (BATCH * SEQ)          // 4096
#define QKV_N  4096                   // 2048 q | 1024 k | 1024 v

typedef __attribute__((ext_vector_type(8))) __bf16 bf16x8;
typedef __attribute__((ext_vector_type(4))) float  f32x4;

static __device__ __forceinline__ f32x4 mfma16(bf16x8 a, bf16x8 b, f32x4 c) {
    return __builtin_amdgcn_mfma_f32_16x16x32_bf16(a, b, c, 0, 0, 0);
}
static __device__ __forceinline__ float sigma_f(float x) {
    return x > 0.f ? x + 1.f : __expf(x);   // elu(x)+1
}

// ---------- workspace layout (bytes) ----------
#define OFF_QKV  0ull                              // float [4096][4096]   64 MB
#define OFF_SQ   67108864ull                       // bf16  (b,h,S,128)    16 MB
#define OFF_QR   83886080ull                       // bf16  (b,h,S,128)    16 MB
#define OFF_KR   100663296ull                      // bf16  (b,kvh,S,128)   8 MB
#define OFF_VT   109051904ull                      // bf16  (b,kvh,128,S)   8 MB
#define OFF_ND   117440512ull                      // float (b,h,S)       256 KB
#define OFF_CB   117702656ull                      // bf16  [4096][2048]   16 MB
#define OFF_PART 134479872ull                      // float 16*(b,kvh,128,128) 16 MB
#define NSPLIT 16

// =====================================================================
// K1 / K8: tiled bf16-MFMA GEMM, C = A @ B (fp32 out).
// B selected per 64-col block among 3 region pointers (fused QKV).
// =====================================================================
template <typename TA>
__global__ __launch_bounds__(256) void gemm_k(
    const TA* __restrict__ A,
    const float* __restrict__ B0, const float* __restrict__ B1, const float* __restrict__ B2,
    float* __restrict__ C,
    int K, int Ntot, int bnd1, int bnd2, int ldb0, int ldb1, int ldb2)
{
    __shared__ __align__(16) __bf16 As[64][40];   // [m][k]
    __shared__ __align__(16) __bf16 Bs[64][40];   // [n][k]  (B^T tile)

    const int tid  = threadIdx.x;
    const int wave = tid >> 6, lane = tid & 63;
    const int l15 = lane & 15, l4 = lane >> 4;
    const int m0 = blockIdx.x * 64;
    const int n0 = blockIdx.y * 64;

    const float* Bp; int ldB, nc0;
    if (n0 < bnd1)      { Bp = B0; ldB = ldb0; nc0 = n0; }
    else if (n0 < bnd2) { Bp = B1; ldB = ldb1; nc0 = n0 - bnd1; }
    else                { Bp = B2; ldB = ldb2; nc0 = n0 - bnd2; }

    f32x4 acc[4] = {};

    const int arow = tid >> 2, ac8 = tid & 3;      // A: 64 rows x 4 chunks of 8
    const int bkr  = tid >> 3, bn8 = tid & 7;      // B: 32 k-rows x 8 chunks of 8

    for (int kb = 0; kb < K; kb += 32) {
        // ---- stage A (convert to bf16) ----
        {
            const TA* src = A + (size_t)(m0 + arow) * K + kb + ac8 * 8;
            bf16x8 t;
            if constexpr (sizeof(TA) == 4) {
                const float4 v0 = *reinterpret_cast<const float4*>(src);
                const float4 v1 = *reinterpret_cast<const float4*>(src + 4);
                t[0]=(__bf16)v0.x; t[1]=(__bf16)v0.y; t[2]=(__bf16)v0.z; t[3]=(__bf16)v0.w;
                t[4]=(__bf16)v1.x; t[5]=(__bf16)v1.y; t[6]=(__bf16)v1.z; t[7]=(__bf16)v1.w;
            } else {
                t = *reinterpret_cast<const bf16x8*>(src);
            }
            *reinterpret_cast<bf16x8*>(&As[arow][ac8 * 8]) = t;
        }
        // ---- stage B transposed ----
        {
            const float* src = Bp + (size_t)(kb + bkr) * ldB + nc0 + bn8 * 8;
            const float4 v0 = *reinterpret_cast<const float4*>(src);
            const float4 v1 = *reinterpret_cast<const float4*>(src + 4);
            float vv[8] = {v0.x, v0.y, v0.z, v0.w, v1.x, v1.y, v1.z, v1.w};
            #pragma unroll
            for (int j = 0; j < 8; ++j) Bs[bn8 * 8 + j][bkr] = (__bf16)vv[j];
        }
        __syncthreads();

        bf16x8 a = *reinterpret_cast<bf16x8*>(&As[wave * 16 + l15][l4 * 8]);
        #pragma unroll
        for (int nc = 0; nc < 4; ++nc) {
            bf16x8 b = *reinterpret_cast<bf16x8*>(&Bs[nc * 16 + l15][l4 * 8]);
            acc[nc] = mfma16(a, b, acc[nc]);
        }
        __syncthreads();
    }

    #pragma unroll
    for (int nc = 0; nc < 4; ++nc)
        #pragma unroll
        for (int r = 0; r < 4; ++r) {
            int row = m0 + wave * 16 + l4 * 4 + r;
            int col = n0 + nc * 16 + l15;
            C[(size_t)row * Ntot + col] = acc[nc][r];
        }
}

// =====================================================================
// K2: sigma_q, norm dots, RoPE(q,k), V^T  — one block per (b,h,s)
// =====================================================================
__global__ void prep_k(const float* __restrict__ qkv, const float* __restrict__ norm_in,
                       const int* __restrict__ pos_ids,
                       __bf16* __restrict__ sq, __bf16* __restrict__ qr,
                       __bf16* __restrict__ kr, __bf16* __restrict__ vt,
                       float* __restrict__ nd)
{
    const int s = blockIdx.x, h = blockIdx.y, b = blockIdx.z, d = threadIdx.x;
    __shared__ float row[128];
    __shared__ float red[128];

    const float* qrow = qkv + (size_t)(b * SEQ + s) * QKV_N;
    float qv = qrow[h * 128 + d];
    float sqv = sigma_f(qv);
    sq[((size_t)(b * NH + h) * SEQ + s) * 128 + d] = (__bf16)sqv;

    red[d] = sqv * norm_in[(b * NKV + (h & 7)) * 128 + d];
    row[d] = qv;
    __syncthreads();
    for (int off = 64; off > 0; off >>= 1) {
        if (d < off) red[d] += red[d + off];
        __syncthreads();
    }
    if (d == 0) nd[(size_t)(b * NH + h) * SEQ + s] = red[0];

    // RoPE
    const int pos = pos_ids[s];
    const int j = d & 63;
    float inv = expf(-((float)(2 * j) / 128.f) * 9.210340371976184f); // ln(10000)
    float ang = (float)pos * inv;
    float c, sn;
    sincosf(ang, &sn, &c);
    float rot = (d < 64) ? -row[d + 64] : row[d - 64];
    qr[((size_t)(b * NH + h) * SEQ + s) * 128 + d] = (__bf16)(qv * c + rot * sn);

    if (h < NKV) {
        float kv = qrow[2048 + h * 128 + d];
        float vv = qrow[3072 + h * 128 + d];
        __syncthreads();
        row[d] = kv;
        __syncthreads();
        float rotk = (d < 64) ? -row[d + 64] : row[d - 64];
        kr[((size_t)(b * NKV + h) * SEQ + s) * 128 + d] = (__bf16)(kv * c + rotk * sn);
        vt[((size_t)((b * NKV + h) * 128 + d)) * SEQ + s] = (__bf16)vv;
    }
}

// =====================================================================
// K3: memory_output = (sigma_q @ mem) / nd, write g*val into combined
// =====================================================================
__global__ __launch_bounds__(256) void memout_k(const __bf16* __restrict__ sq,
                                                const float* __restrict__ mem_in,
                                                const float* __restrict__ nd,
                                                const float* __restrict__ gate,
                                                __bf16* __restrict__ cb)
{
    __shared__ __align__(16) __bf16 mt[128][136];   // mem^T [e][d]
    const int tid = threadIdx.x;
    const int h = blockIdx.y, b = blockIdx.z;
    const int s0 = blockIdx.x * 64;

    const float* mem = mem_in + (size_t)(b * NKV + (h & 7)) * 16384;
    for (int i = tid; i < 16384; i += 256) {
        int dd = i >> 7, e = i & 127;
        mt[e][dd] = (__bf16)mem[i];
    }
    __syncthreads();

    const int wave = tid >> 6, lane = tid & 63, l15 = lane & 15, l4 = lane >> 4;
    f32x4 acc[8] = {};
    const __bf16* sqb = sq + ((size_t)(b * NH + h) * SEQ + s0 + wave * 16 + l15) * 128;
    #pragma unroll
    for (int kb = 0; kb < 4; ++kb) {
        bf16x8 a = *reinterpret_cast<const bf16x8*>(sqb + kb * 32 + l4 * 8);
        #pragma unroll
        for (int nc = 0; nc < 8; ++nc) {
            bf16x8 bb = *reinterpret_cast<bf16x8*>(&mt[nc * 16 + l15][kb * 32 + l4 * 8]);
            acc[nc] = mfma16(a, bb, acc[nc]);
        }
    }
    float g = 1.f / (1.f + __expf(-gate[h]));
    #pragma unroll
    for (int r = 0; r < 4; ++r) {
        int srow = s0 + wave * 16 + l4 * 4 + r;
        float scl = g / nd[(size_t)(b * NH + h) * SEQ + srow];
        __bf16* cbp = cb + (size_t)(b * SEQ + srow) * HID + h * 128;
        #pragma unroll
        for (int nc = 0; nc < 8; ++nc)
            cbp[nc * 16 + l15] = (__bf16)(acc[nc][r] * scl);
    }
}

// =====================================================================
// K4: updated_norm = norm_in + sum_s sigma_k
// =====================================================================
__global__ void normupd_k(const float* __restrict__ qkv, const float* __restrict__ norm_in,
                          float* __restrict__ out_norm)
{
    const int h = blockIdx.x, b = blockIdx.y;
    const int t = threadIdx.x, d = t & 127, sg = t >> 7;   // 512 threads: 4 s-groups
    __shared__ float pr[4][128];
    float acc = 0.f;
    for (int s = sg; s < SEQ; s += 4) {
        float kv = qkv[(size_t)(b * SEQ + s) * QKV_N + 2048 + h * 128 + d];
        acc += sigma_f(kv);
    }
    pr[sg][d] = acc;
    __syncthreads();
    if (sg == 0)
        out_norm[(b * NKV + h) * 128 + d] =
            norm_in[(b * NKV + h) * 128 + d] + pr[0][d] + pr[1][d] + pr[2][d] + pr[3][d];
}

// =====================================================================
// K5: updated_memory partials: part[sp] = sigma_k^T @ v over s-chunk
// =====================================================================
__global__ __launch_bounds__(256) void memupd_k(const float* __restrict__ qkv,
                                                float* __restrict__ part)
{
    const int sp = blockIdx.x, h = blockIdx.y, b = blockIdx.z;
    const int tid = threadIdx.x;
    const int tx = tid & 15, ty = tid >> 4;   // d-block tx*8, e-block ty*8
    __shared__ __align__(16) float sk[8][128];
    __shared__ __align__(16) float sv[8][128];
    float acc[8][8] = {};

    const int s0 = sp * (SEQ / NSPLIT);
    for (int so = 0; so < SEQ / NSPLIT; so += 8) {
        for (int i = tid; i < 8 * 128; i += 256) {
            int rr = i >> 7, dd = i & 127;
            const float* rowp = qkv + (size_t)(b * SEQ + s0 + so + rr) * QKV_N;
            sk[rr][dd] = sigma_f(rowp[2048 + h * 128 + dd]);
            sv[rr][dd] = rowp[3072 + h * 128 + dd];
        }
        __syncthreads();
        #pragma unroll
        for (int rr = 0; rr < 8; ++rr) {
            float4 k0 = *reinterpret_cast<float4*>(&sk[rr][tx * 8]);
            float4 k1 = *reinterpret_cast<float4*>(&sk[rr][tx * 8 + 4]);
            float4 v0 = *reinterpret_cast<float4*>(&sv[rr][ty * 8]);
            float4 v1 = *reinterpret_cast<float4*>(&sv[rr][ty * 8 + 4]);
            float kreg[8] = {k0.x,k0.y,k0.z,k0.w,k1.x,k1.y,k1.z,k1.w};
            float vreg[8] = {v0.x,v0.y,v0.z,v0.w,v1.x,v1.y,v1.z,v1.w};
            #pragma unroll
            for (int i = 0; i < 8; ++i)
                #pragma unroll
                for (int j2 = 0; j2 < 8; ++j2)
                    acc[i][j2] += kreg[i] * vreg[j2];
        }
        __syncthreads();
    }
    float* pb = part + ((size_t)sp * (BATCH * NKV) + b * NKV + h) * 16384;
    #pragma unroll
    for (int i = 0; i < 8; ++i)
        #pragma unroll
        for (int j2 = 0; j2 < 8; ++j2)
            pb[(tx * 8 + i) * 128 + ty * 8 + j2] = acc[i][j2];
}

// K6: reduce partials + memory_in
__global__ void memred_k(const float* __restrict__ part, const float* __restrict__ mem_in,
                         float* __restrict__ out_mem)
{
    const size_t i = (size_t)blockIdx.x * 256 + threadIdx.x;   // 262144 total
    float a = mem_in[i];
    #pragma unroll
    for (int sp = 0; sp < NSPLIT; ++sp) a += part[(size_t)sp * 262144 + i];
    out_mem[i] = a;
}

// =====================================================================
// K7: flash causal attention; epilogue adds (1-g)*attn into combined
// =====================================================================
__global__ __launch_bounds__(256) void attn_k(const __bf16* __restrict__ qr,
                                              const __bf16* __restrict__ kr,
                                              const __bf16* __restrict__ vt,
                                              const float* __restrict__ gate,
                                              __bf16* __restrict__ cb)
{
    __shared__ __align__(16) __bf16 plds[4][16][40];
    const int tid = threadIdx.x, wave = tid >> 6, lane = tid & 63;
    const int l15 = lane & 15, l4 = lane >> 4;
    const int h = blockIdx.y, b = blockIdx.z;
    const int q0 = blockIdx.x * 64 + wave * 16;
    const int kvh = h >> 1;

    const __bf16* qbase = qr + ((size_t)(b * NH + h) * SEQ + q0 + l15) * 128;
    bf16x8 af[4];
    #pragma unroll
    for (int kb = 0; kb < 4; ++kb) af[kb] = *reinterpret_cast<const bf16x8*>(qbase + kb * 32 + l4 * 8);

    const __bf16* kbase = kr + (size_t)(b * NKV + kvh) * SEQ * 128;
    const __bf16* vbase = vt + (size_t)(b * NKV + kvh) * 128 * SEQ;

    f32x4 o[8] = {};
    float mi[4] = {-1e30f, -1e30f, -1e30f, -1e30f};
    float li[4] = {0.f, 0.f, 0.f, 0.f};
    const float scale = 0.08838834764831845f;   // 1/sqrt(128)
    const int qmax = q0 + 15;

    for (int kt = 0; kt <= qmax; kt += 32) {
        f32x4 s0v = {}, s1v = {};
        #pragma unroll
        for (int kb = 0; kb < 4; ++kb) {
            bf16x8 b0 = *reinterpret_cast<const bf16x8*>(kbase + (size_t)(kt + l15) * 128 + kb * 32 + l4 * 8);
            bf16x8 b1 = *reinterpret_cast<const bf16x8*>(kbase + (size_t)(kt + 16 + l15) * 128 + kb * 32 + l4 * 8);
            s0v = mfma16(af[kb], b0, s0v);
            s1v = mfma16(af[kb], b1, s1v);
        }
        const int key0 = kt + l15, key1 = kt + 16 + l15;
        float p0[4], p1[4], mnew[4], alpha[4];
        #pragma unroll
        for (int r = 0; r < 4; ++r) {
            int qrow = q0 + l4 * 4 + r;
            p0[r] = (key0 <= qrow) ? s0v[r] * scale : -1e30f;
            p1[r] = (key1 <= qrow) ? s1v[r] * scale : -1e30f;
            float mx = fmaxf(p0[r], p1[r]);
            #pragma unroll
            for (int msk = 1; msk < 16; msk <<= 1) mx = fmaxf(mx, __shfl_xor(mx, msk));
            mnew[r] = fmaxf(mi[r], mx);
        }
        #pragma unroll
        for (int r = 0; r < 4; ++r) {
            alpha[r] = __expf(mi[r] - mnew[r]);
            p0[r] = __expf(p0[r] - mnew[r]);
            p1[r] = __expf(p1[r] - mnew[r]);
            float rs = p0[r] + p1[r];
            #pragma unroll
            for (int msk = 1; msk < 16; msk <<= 1) rs += __shfl_xor(rs, msk);
            li[r] = li[r] * alpha[r] + rs;
            mi[r] = mnew[r];
        }
        #pragma unroll
        for (int nc = 0; nc < 8; ++nc)
            #pragma unroll
            for (int r = 0; r < 4; ++r) o[nc][r] *= alpha[r];
        // P: C-layout -> A-layout through per-wave LDS
        #pragma unroll
        for (int r = 0; r < 4; ++r) {
            plds[wave][l4 * 4 + r][l15]      = (__bf16)p0[r];
            plds[wave][l4 * 4 + r][16 + l15] = (__bf16)p1[r];
        }
        bf16x8 ap = *reinterpret_cast<bf16x8*>(&plds[wave][l15][l4 * 8]);
        #pragma unroll
        for (int nc = 0; nc < 8; ++nc) {
            bf16x8 bv = *reinterpret_cast<const bf16x8*>(vbase + (size_t)(nc * 16 + l15) * SEQ + kt + l4 * 8);
            o[nc] = mfma16(ap, bv, o[nc]);
        }
    }

    float g = 1.f / (1.f + __expf(-gate[h]));
    float gi = 1.f - g;
    #pragma unroll
    for (int r = 0; r < 4; ++r) {
        int qrow = q0 + l4 * 4 + r;
        float inv = gi / li[r];
        __bf16* cbp = cb + (size_t)(b * SEQ + qrow) * HID + h * 128;
        #pragma unroll
        for (int nc = 0; nc < 8; ++nc) {
            int dd = nc * 16 + l15;
            float prev = (float)cbp[dd];
            cbp[dd] = (__bf16)(prev + o[nc][r] * inv);
        }
    }
}

// =====================================================================
extern "C" void kernel_launch(void* const* d_in, const int* in_sizes, int n_in,
                              void* d_out, int out_size, void* d_ws, size_t ws_size,
                              hipStream_t stream)
{
    const float* hidden  = (const float*)d_in[0];
    const float* Wq      = (const float*)d_in[1];
    const float* Wk      = (const float*)d_in[2];
    const float* Wv      = (const float*)d_in[3];
    const float* Wo      = (const float*)d_in[4];
    const float* gate    = (const float*)d_in[5];
    const float* mem_in  = (const float*)d_in[6];
    const float* norm_in = (const float*)d_in[7];
    const int*   pos     = (const int*)d_in[8];

    float* out_final = (float*)d_out;                  // (B,S,HID)
    float* out_mem   = out_final + (size_t)BATCH * SEQ * HID;     // (B,8,128,128)
    float* out_norm  = out_mem + (size_t)BATCH * NKV * 128 * 128; // (B,8,1,128)

    char* ws = (char*)d_ws;
    float*  qkv  = (float*)(ws + OFF_QKV);
    __bf16* sq   = (__bf16*)(ws + OFF_SQ);
    __bf16* qrb  = (__bf16*)(ws + OFF_QR);
    __bf16* krb  = (__bf16*)(ws + OFF_KR);
    __bf16* vtb  = (__bf16*)(ws + OFF_VT);
    float*  nd   = (float*)(ws + OFF_ND);
    __bf16* cb   = (__bf16*)(ws + OFF_CB);
    float*  part = (float*)(ws + OFF_PART);

    // 1. fused QKV projection: [4096 x 2048] @ [2048 x (2048|1024|1024)]
    gemm_k<float><<<dim3(M_ROWS / 64, QKV_N / 64), 256, 0, stream>>>(
        hidden, Wq, Wk, Wv, qkv, HID, QKV_N, 2048, 3072, 2048, 1024, 1024);

    // 2. sigma_q / norm-dot / RoPE / V^T
    prep_k<<<dim3(SEQ, NH, BATCH), 128, 0, stream>>>(qkv, norm_in, pos, sq, qrb, krb, vtb, nd);

    // 3. memory_output -> combined (g * memout / nd)
    memout_k<<<dim3(SEQ / 64, NH, BATCH), 256, 0, stream>>>(sq, mem_in, nd, gate, cb);

    // 4. updated_norm
    normupd_k<<<dim3(NKV, BATCH), 512, 0, stream>>>(qkv, norm_in, out_norm);

    // 5/6. updated_memory
    memupd_k<<<dim3(NSPLIT, NKV, BATCH), 256, 0, stream>>>(qkv, part);
    memred_k<<<(BATCH * NKV * 128 * 128) / 256, 256, 0, stream>>>(part, mem_in, out_mem);

    // 7. causal attention, adds (1-g)*attn into combined
    attn_k<<<dim3(SEQ / 64, NH, BATCH), 256, 0, stream>>>(qrb, krb, vtb, gate, cb);

    // 8. output projection: combined @ Wo
    gemm_k<__bf16><<<dim3(M_ROWS / 64, HID / 64), 256, 0, stream>>>(
        cb, Wo, Wo, Wo, out_final, HID, HID, HID, 2 * HID, HID, HID, HID);
}

// Round 2
// 1012.919 us; speedup vs baseline: 1.3556x; 1.3556x over previous
//
#include <hip/hip_runtime.h>

// ---------- problem constants ----------
#define BATCH 2
#define SEQ   2048
#define HID   2048
#define NH    16
#define NKV   8
#define HD    128
#define M_ROWS (BATCH * SEQ)          // 4096
#define QKV_N  4096                   // 2048 q | 1024 k | 1024 v

typedef __attribute__((ext_vector_type(8))) __bf16 bf16x8;
typedef __attribute__((ext_vector_type(4))) float  f32x4;

static __device__ __forceinline__ f32x4 mfma16(bf16x8 a, bf16x8 b, f32x4 c) {
    return __builtin_amdgcn_mfma_f32_16x16x32_bf16(a, b, c, 0, 0, 0);
}
static __device__ __forceinline__ float sigma_f(float x) {
    return x > 0.f ? x + 1.f : __expf(x);   // elu(x)+1
}

// ---------- workspace layout (bytes) ----------
#define OFF_QKV  0ull                              // float [4096][4096]   64 MB
#define OFF_SQ   67108864ull                       // bf16  (b,h,S,128)    16 MB
#define OFF_QR   83886080ull                       // bf16  (b,h,S,128)    16 MB
#define OFF_KR   100663296ull                      // bf16  (b,kvh,S,128)   8 MB
#define OFF_VT   109051904ull                      // bf16  (b,kvh,128,S)   8 MB
#define OFF_ND   117440512ull                      // float (b,h,S)       256 KB
#define OFF_CB   117702656ull                      // bf16  [4096][2048]   16 MB
#define OFF_PART 134479872ull                      // float 16*(b,kvh,128,128) 16 MB
#define NSPLIT 16

// =====================================================================
// K1 / K8: tiled bf16-MFMA GEMM, C = A @ B (fp32 out).
// B selected per 64-col block among 3 region pointers (fused QKV).
// =====================================================================
template <typename TA>
__global__ __launch_bounds__(256) void gemm_k(
    const TA* __restrict__ A,
    const float* __restrict__ B0, const float* __restrict__ B1, const float* __restrict__ B2,
    float* __restrict__ C,
    int K, int Ntot, int bnd1, int bnd2, int ldb0, int ldb1, int ldb2)
{
    __shared__ __align__(16) __bf16 As[64][40];   // [m][k]
    __shared__ __align__(16) __bf16 Bs[64][40];   // [n][k]  (B^T tile)

    const int tid  = threadIdx.x;
    const int wave = tid >> 6, lane = tid & 63;
    const int l15 = lane & 15, l4 = lane >> 4;
    const int m0 = blockIdx.x * 64;
    const int n0 = blockIdx.y * 64;

    const float* Bp; int ldB, nc0;
    if (n0 < bnd1)      { Bp = B0; ldB = ldb0; nc0 = n0; }
    else if (n0 < bnd2) { Bp = B1; ldB = ldb1; nc0 = n0 - bnd1; }
    else                { Bp = B2; ldB = ldb2; nc0 = n0 - bnd2; }

    f32x4 acc[4] = {};

    const int arow = tid >> 2, ac8 = tid & 3;      // A: 64 rows x 4 chunks of 8
    const int bkr  = tid >> 3, bn8 = tid & 7;      // B: 32 k-rows x 8 chunks of 8

    for (int kb = 0; kb < K; kb += 32) {
        // ---- stage A (convert to bf16) ----
        {
            const TA* src = A + (size_t)(m0 + arow) * K + kb + ac8 * 8;
            bf16x8 t;
            if constexpr (sizeof(TA) == 4) {
                const float4 v0 = *reinterpret_cast<const float4*>(src);
                const float4 v1 = *reinterpret_cast<const float4*>(src + 4);
                t[0]=(__bf16)v0.x; t[1]=(__bf16)v0.y; t[2]=(__bf16)v0.z; t[3]=(__bf16)v0.w;
                t[4]=(__bf16)v1.x; t[5]=(__bf16)v1.y; t[6]=(__bf16)v1.z; t[7]=(__bf16)v1.w;
            } else {
                t = *reinterpret_cast<const bf16x8*>(src);
            }
            *reinterpret_cast<bf16x8*>(&As[arow][ac8 * 8]) = t;
        }
        // ---- stage B transposed ----
        {
            const float* src = Bp + (size_t)(kb + bkr) * ldB + nc0 + bn8 * 8;
            const float4 v0 = *reinterpret_cast<const float4*>(src);
            const float4 v1 = *reinterpret_cast<const float4*>(src + 4);
            float vv[8] = {v0.x, v0.y, v0.z, v0.w, v1.x, v1.y, v1.z, v1.w};
            #pragma unroll
            for (int j = 0; j < 8; ++j) Bs[bn8 * 8 + j][bkr] = (__bf16)vv[j];
        }
        __syncthreads();

        bf16x8 a = *reinterpret_cast<bf16x8*>(&As[wave * 16 + l15][l4 * 8]);
        #pragma unroll
        for (int nc = 0; nc < 4; ++nc) {
            bf16x8 b = *reinterpret_cast<bf16x8*>(&Bs[nc * 16 + l15][l4 * 8]);
            acc[nc] = mfma16(a, b, acc[nc]);
        }
        __syncthreads();
    }

    #pragma unroll
    for (int nc = 0; nc < 4; ++nc)
        #pragma unroll
        for (int r = 0; r < 4; ++r) {
            int row = m0 + wave * 16 + l4 * 4 + r;
            int col = n0 + nc * 16 + l15;
            C[(size_t)row * Ntot + col] = acc[nc][r];
        }
}

// =====================================================================
// K2: sigma_q, norm dots, RoPE(q,k), V^T  — one block per (b,h,s)
// qr is pre-scaled by 1/sqrt(HD) (only consumer is attention QK^T).
// =====================================================================
__global__ void prep_k(const float* __restrict__ qkv, const float* __restrict__ norm_in,
                       const int* __restrict__ pos_ids,
                       __bf16* __restrict__ sq, __bf16* __restrict__ qr,
                       __bf16* __restrict__ kr, __bf16* __restrict__ vt,
                       float* __restrict__ nd)
{
    const int s = blockIdx.x, h = blockIdx.y, b = blockIdx.z, d = threadIdx.x;
    __shared__ float row[128];
    __shared__ float red[128];

    const float* qrow = qkv + (size_t)(b * SEQ + s) * QKV_N;
    float qv = qrow[h * 128 + d];
    float sqv = sigma_f(qv);
    sq[((size_t)(b * NH + h) * SEQ + s) * 128 + d] = (__bf16)sqv;

    red[d] = sqv * norm_in[(b * NKV + (h & 7)) * 128 + d];
    row[d] = qv;
    __syncthreads();
    for (int off = 64; off > 0; off >>= 1) {
        if (d < off) red[d] += red[d + off];
        __syncthreads();
    }
    if (d == 0) nd[(size_t)(b * NH + h) * SEQ + s] = red[0];

    // RoPE
    const int pos = pos_ids[s];
    const int j = d & 63;
    float inv = expf(-((float)(2 * j) / 128.f) * 9.210340371976184f); // ln(10000)
    float ang = (float)pos * inv;
    float c, sn;
    sincosf(ang, &sn, &c);
    float rot = (d < 64) ? -row[d + 64] : row[d - 64];
    const float scale = 0.08838834764831845f;   // 1/sqrt(128), folded into q
    qr[((size_t)(b * NH + h) * SEQ + s) * 128 + d] = (__bf16)((qv * c + rot * sn) * scale);

    if (h < NKV) {
        float kv = qrow[2048 + h * 128 + d];
        float vv = qrow[3072 + h * 128 + d];
        __syncthreads();
        row[d] = kv;
        __syncthreads();
        float rotk = (d < 64) ? -row[d + 64] : row[d - 64];
        kr[((size_t)(b * NKV + h) * SEQ + s) * 128 + d] = (__bf16)(kv * c + rotk * sn);
        vt[((size_t)((b * NKV + h) * 128 + d)) * SEQ + s] = (__bf16)vv;
    }
}

// =====================================================================
// K3: memory_output = (sigma_q @ mem) / nd, write g*val into combined
// =====================================================================
__global__ __launch_bounds__(256) void memout_k(const __bf16* __restrict__ sq,
                                                const float* __restrict__ mem_in,
                                                const float* __restrict__ nd,
                                                const float* __restrict__ gate,
                                                __bf16* __restrict__ cb)
{
    __shared__ __align__(16) __bf16 mt[128][136];   // mem^T [e][d]
    const int tid = threadIdx.x;
    const int h = blockIdx.y, b = blockIdx.z;
    const int s0 = blockIdx.x * 64;

    const float* mem = mem_in + (size_t)(b * NKV + (h & 7)) * 16384;
    for (int i = tid; i < 16384; i += 256) {
        int dd = i >> 7, e = i & 127;
        mt[e][dd] = (__bf16)mem[i];
    }
    __syncthreads();

    const int wave = tid >> 6, lane = tid & 63, l15 = lane & 15, l4 = lane >> 4;
    f32x4 acc[8] = {};
    const __bf16* sqb = sq + ((size_t)(b * NH + h) * SEQ + s0 + wave * 16 + l15) * 128;
    #pragma unroll
    for (int kb = 0; kb < 4; ++kb) {
        bf16x8 a = *reinterpret_cast<const bf16x8*>(sqb + kb * 32 + l4 * 8);
        #pragma unroll
        for (int nc = 0; nc < 8; ++nc) {
            bf16x8 bb = *reinterpret_cast<bf16x8*>(&mt[nc * 16 + l15][kb * 32 + l4 * 8]);
            acc[nc] = mfma16(a, bb, acc[nc]);
        }
    }
    float g = 1.f / (1.f + __expf(-gate[h]));
    #pragma unroll
    for (int r = 0; r < 4; ++r) {
        int srow = s0 + wave * 16 + l4 * 4 + r;
        float scl = g / nd[(size_t)(b * NH + h) * SEQ + srow];
        __bf16* cbp = cb + (size_t)(b * SEQ + srow) * HID + h * 128;
        #pragma unroll
        for (int nc = 0; nc < 8; ++nc)
            cbp[nc * 16 + l15] = (__bf16)(acc[nc][r] * scl);
    }
}

// =====================================================================
// K4: updated_norm = norm_in + sum_s sigma_k
// =====================================================================
__global__ void normupd_k(const float* __restrict__ qkv, const float* __restrict__ norm_in,
                          float* __restrict__ out_norm)
{
    const int h = blockIdx.x, b = blockIdx.y;
    const int t = threadIdx.x, d = t & 127, sg = t >> 7;   // 512 threads: 4 s-groups
    __shared__ float pr[4][128];
    float acc = 0.f;
    for (int s = sg; s < SEQ; s += 4) {
        float kv = qkv[(size_t)(b * SEQ + s) * QKV_N + 2048 + h * 128 + d];
        acc += sigma_f(kv);
    }
    pr[sg][d] = acc;
    __syncthreads();
    if (sg == 0)
        out_norm[(b * NKV + h) * 128 + d] =
            norm_in[(b * NKV + h) * 128 + d] + pr[0][d] + pr[1][d] + pr[2][d] + pr[3][d];
}

// =====================================================================
// K5: updated_memory partials: part[sp] = sigma_k^T @ v over s-chunk
// =====================================================================
__global__ __launch_bounds__(256) void memupd_k(const float* __restrict__ qkv,
                                                float* __restrict__ part)
{
    const int sp = blockIdx.x, h = blockIdx.y, b = blockIdx.z;
    const int tid = threadIdx.x;
    const int tx = tid & 15, ty = tid >> 4;   // d-block tx*8, e-block ty*8
    __shared__ __align__(16) float sk[8][128];
    __shared__ __align__(16) float sv[8][128];
    float acc[8][8] = {};

    const int s0 = sp * (SEQ / NSPLIT);
    for (int so = 0; so < SEQ / NSPLIT; so += 8) {
        for (int i = tid; i < 8 * 128; i += 256) {
            int rr = i >> 7, dd = i & 127;
            const float* rowp = qkv + (size_t)(b * SEQ + s0 + so + rr) * QKV_N;
            sk[rr][dd] = sigma_f(rowp[2048 + h * 128 + dd]);
            sv[rr][dd] = rowp[3072 + h * 128 + dd];
        }
        __syncthreads();
        #pragma unroll
        for (int rr = 0; rr < 8; ++rr) {
            float4 k0 = *reinterpret_cast<float4*>(&sk[rr][tx * 8]);
            float4 k1 = *reinterpret_cast<float4*>(&sk[rr][tx * 8 + 4]);
            float4 v0 = *reinterpret_cast<float4*>(&sv[rr][ty * 8]);
            float4 v1 = *reinterpret_cast<float4*>(&sv[rr][ty * 8 + 4]);
            float kreg[8] = {k0.x,k0.y,k0.z,k0.w,k1.x,k1.y,k1.z,k1.w};
            float vreg[8] = {v0.x,v0.y,v0.z,v0.w,v1.x,v1.y,v1.z,v1.w};
            #pragma unroll
            for (int i = 0; i < 8; ++i)
                #pragma unroll
                for (int j2 = 0; j2 < 8; ++j2)
                    acc[i][j2] += kreg[i] * vreg[j2];
        }
        __syncthreads();
    }
    float* pb = part + ((size_t)sp * (BATCH * NKV) + b * NKV + h) * 16384;
    #pragma unroll
    for (int i = 0; i < 8; ++i)
        #pragma unroll
        for (int j2 = 0; j2 < 8; ++j2)
            pb[(tx * 8 + i) * 128 + ty * 8 + j2] = acc[i][j2];
}

// K6: reduce partials + memory_in
__global__ void memred_k(const float* __restrict__ part, const float* __restrict__ mem_in,
                         float* __restrict__ out_mem)
{
    const size_t i = (size_t)blockIdx.x * 256 + threadIdx.x;   // 262144 total
    float a = mem_in[i];
    #pragma unroll
    for (int sp = 0; sp < NSPLIT; ++sp) a += part[(size_t)sp * 262144 + i];
    out_mem[i] = a;
}

// =====================================================================
// K7: flash causal attention (balanced + LDS-staged).
// Each block handles q-tiles x and 31-x (64 rows each) -> uniform 2112
// keys/block. K/V chunks of 64 keys staged in LDS, shared by 4 waves.
// Epilogue adds (1-g)*attn into combined.
// =====================================================================
__global__ __launch_bounds__(256) void attn_k(const __bf16* __restrict__ qr,
                                              const __bf16* __restrict__ kr,
                                              const __bf16* __restrict__ vt,
                                              const float* __restrict__ gate,
                                              __bf16* __restrict__ cb)
{
    __shared__ __align__(16) __bf16 Ks[64][136];    // [key][d]   (+8 pad)
    __shared__ __align__(16) __bf16 Vs[128][72];    // [d][key]   (+8 pad)
    __shared__ __align__(16) __bf16 plds[4][16][72];// per-wave P transpose

    const int tid = threadIdx.x, wave = tid >> 6, lane = tid & 63;
    const int l15 = lane & 15, l4 = lane >> 4;
    const int h = blockIdx.y, b = blockIdx.z;
    const int kvh = h >> 1;

    const __bf16* kbase = kr + (size_t)(b * NKV + kvh) * SEQ * 128;
    const __bf16* vbase = vt + (size_t)(b * NKV + kvh) * 128 * SEQ;

    const float g  = 1.f / (1.f + __expf(-gate[h]));
    const float gi = 1.f - g;

    // staging indices
    const int k_row = tid >> 4, k_col = (tid & 15) * 8;   // K: 16 rows/round
    const int v_row = tid >> 3, v_col = (tid & 7) * 8;    // V: 32 rows/round

    #pragma unroll 1
    for (int tile = 0; tile < 2; ++tile) {
        const int q0 = (tile == 0 ? blockIdx.x : 31 - blockIdx.x) * 64;
        const int qw = q0 + wave * 16;                     // this wave's q rows

        // Q fragments (pre-scaled by 1/sqrt(d) in prep)
        const __bf16* qbase = qr + ((size_t)(b * NH + h) * SEQ + qw + l15) * 128;
        bf16x8 af[4];
        #pragma unroll
        for (int kb = 0; kb < 4; ++kb)
            af[kb] = *reinterpret_cast<const bf16x8*>(qbase + kb * 32 + l4 * 8);

        f32x4 o[8] = {};
        float mi[4] = {-1e30f, -1e30f, -1e30f, -1e30f};
        float li[4] = {0.f, 0.f, 0.f, 0.f};

        #pragma unroll 1
        for (int kt = 0; kt < q0 + 64; kt += 64) {
            // ---- cooperative staging of K (64x128) and V^T (128x64) ----
            #pragma unroll
            for (int r = 0; r < 4; ++r) {
                *reinterpret_cast<bf16x8*>(&Ks[r * 16 + k_row][k_col]) =
                    *reinterpret_cast<const bf16x8*>(kbase + (size_t)(kt + r * 16 + k_row) * 128 + k_col);
            }
            #pragma unroll
            for (int r = 0; r < 4; ++r) {
                *reinterpret_cast<bf16x8*>(&Vs[r * 32 + v_row][v_col]) =
                    *reinterpret_cast<const bf16x8*>(vbase + (size_t)(r * 32 + v_row) * SEQ + kt + v_col);
            }
            __syncthreads();

            // ---- QK^T: 16 q-rows x 64 keys ----
            f32x4 sv[4] = {};
            #pragma unroll
            for (int kb = 0; kb < 4; ++kb) {
                #pragma unroll
                for (int sub = 0; sub < 4; ++sub) {
                    bf16x8 bb = *reinterpret_cast<bf16x8*>(&Ks[sub * 16 + l15][kb * 32 + l4 * 8]);
                    sv[sub] = mfma16(af[kb], bb, sv[sub]);
                }
            }

            // ---- online softmax over 64 keys ----
            #pragma unroll
            for (int r = 0; r < 4; ++r) {
                const int qrow = qw + l4 * 4 + r;
                float p[4];
                float mx = -1e30f;
                #pragma unroll
                for (int sub = 0; sub < 4; ++sub) {
                    int key = kt + sub * 16 + l15;
                    p[sub] = (key <= qrow) ? sv[sub][r] : -1e30f;
                    mx = fmaxf(mx, p[sub]);
                }
                #pragma unroll
                for (int msk = 1; msk < 16; msk <<= 1) mx = fmaxf(mx, __shfl_xor(mx, msk));
                const float mnew = fmaxf(mi[r], mx);
                const float alpha = __expf(mi[r] - mnew);
                float rs = 0.f;
                #pragma unroll
                for (int sub = 0; sub < 4; ++sub) {
                    p[sub] = __expf(p[sub] - mnew);
                    rs += p[sub];
                    plds[wave][l4 * 4 + r][sub * 16 + l15] = (__bf16)p[sub];
                }
                #pragma unroll
                for (int msk = 1; msk < 16; msk <<= 1) rs += __shfl_xor(rs, msk);
                li[r] = li[r] * alpha + rs;
                mi[r] = mnew;
                #pragma unroll
                for (int nc = 0; nc < 8; ++nc) o[nc][r] *= alpha;
            }

            // ---- PV: P (A-layout from per-wave LDS) x V^T ----
            bf16x8 ap0 = *reinterpret_cast<bf16x8*>(&plds[wave][l15][l4 * 8]);
            bf16x8 ap1 = *reinterpret_cast<bf16x8*>(&plds[wave][l15][32 + l4 * 8]);
            #pragma unroll
            for (int nc = 0; nc < 8; ++nc) {
                bf16x8 b0 = *reinterpret_cast<bf16x8*>(&Vs[nc * 16 + l15][l4 * 8]);
                bf16x8 b1 = *reinterpret_cast<bf16x8*>(&Vs[nc * 16 + l15][32 + l4 * 8]);
                o[nc] = mfma16(ap0, b0, o[nc]);
                o[nc] = mfma16(ap1, b1, o[nc]);
            }
            __syncthreads();   // protect Ks/Vs before next staging
        }

        // ---- epilogue: add (1-g) * attn / li into combined ----
        #pragma unroll
        for (int r = 0; r < 4; ++r) {
            const int qrow = qw + l4 * 4 + r;
            const float inv = gi / li[r];
            __bf16* cbp = cb + (size_t)(b * SEQ + qrow) * HID + h * 128;
            #pragma unroll
            for (int nc = 0; nc < 8; ++nc) {
                const int dd = nc * 16 + l15;
                float prev = (float)cbp[dd];
                cbp[dd] = (__bf16)(prev + o[nc][r] * inv);
            }
        }
    }
}

// =====================================================================
extern "C" void kernel_launch(void* const* d_in, const int* in_sizes, int n_in,
                              void* d_out, int out_size, void* d_ws, size_t ws_size,
                              hipStream_t stream)
{
    const float* hidden  = (const float*)d_in[0];
    const float* Wq      = (const float*)d_in[1];
    const float* Wk      = (const float*)d_in[2];
    const float* Wv      = (const float*)d_in[3];
    const float* Wo      = (const float*)d_in[4];
    const float* gate    = (const float*)d_in[5];
    const float* mem_in  = (const float*)d_in[6];
    const float* norm_in = (const float*)d_in[7];
    const int*   pos     = (const int*)d_in[8];

    float* out_final = (float*)d_out;                  // (B,S,HID)
    float* out_mem   = out_final + (size_t)BATCH * SEQ * HID;     // (B,8,128,128)
    float* out_norm  = out_mem + (size_t)BATCH * NKV * 128 * 128; // (B,8,1,128)

    char* ws = (char*)d_ws;
    float*  qkv  = (float*)(ws + OFF_QKV);
    __bf16* sq   = (__bf16*)(ws + OFF_SQ);
    __bf16* qrb  = (__bf16*)(ws + OFF_QR);
    __bf16* krb  = (__bf16*)(ws + OFF_KR);
    __bf16* vtb  = (__bf16*)(ws + OFF_VT);
    float*  nd   = (float*)(ws + OFF_ND);
    __bf16* cb   = (__bf16*)(ws + OFF_CB);
    float*  part = (float*)(ws + OFF_PART);

    // 1. fused QKV projection: [4096 x 2048] @ [2048 x (2048|1024|1024)]
    gemm_k<float><<<dim3(M_ROWS / 64, QKV_N / 64), 256, 0, stream>>>(
        hidden, Wq, Wk, Wv, qkv, HID, QKV_N, 2048, 3072, 2048, 1024, 1024);

    // 2. sigma_q / norm-dot / RoPE / V^T
    prep_k<<<dim3(SEQ, NH, BATCH), 128, 0, stream>>>(qkv, norm_in, pos, sq, qrb, krb, vtb, nd);

    // 3. memory_output -> combined (g * memout / nd)
    memout_k<<<dim3(SEQ / 64, NH, BATCH), 256, 0, stream>>>(sq, mem_in, nd, gate, cb);

    // 4. updated_norm
    normupd_k<<<dim3(NKV, BATCH), 512, 0, stream>>>(qkv, norm_in, out_norm);

    // 5/6. updated_memory
    memupd_k<<<dim3(NSPLIT, NKV, BATCH), 256, 0, stream>>>(qkv, part);
    memred_k<<<(BATCH * NKV * 128 * 128) / 256, 256, 0, stream>>>(part, mem_in, out_mem);

    // 7. causal attention (balanced q-tile pairs), adds (1-g)*attn into combined
    attn_k<<<dim3(16, NH, BATCH), 256, 0, stream>>>(qrb, krb, vtb, gate, cb);

    // 8. output projection: combined @ Wo
    gemm_k<__bf16><<<dim3(M_ROWS / 64, HID / 64), 256, 0, stream>>>(
        cb, Wo, Wo, Wo, out_final, HID, HID, HID, 2 * HID, HID, HID, HID);
}

// Round 3
// 683.867 us; speedup vs baseline: 2.0078x; 1.4812x over previous
//
#include <hip/hip_runtime.h>

// ---------- problem constants ----------
#define BATCH 2
#define SEQ   2048
#define HID   2048
#define NH    16
#define NKV   8
#define HD    128
#define M_ROWS (BATCH * SEQ)          // 4096
#define QKV_N  4096                   // 2048 q | 1024 k | 1024 v

typedef __attribute__((ext_vector_type(8))) __bf16 bf16x8;
typedef __attribute__((ext_vector_type(4))) float  f32x4;

static __device__ __forceinline__ f32x4 mfma16(bf16x8 a, bf16x8 b, f32x4 c) {
    return __builtin_amdgcn_mfma_f32_16x16x32_bf16(a, b, c, 0, 0, 0);
}
static __device__ __forceinline__ float sigma_f(float x) {
    return x > 0.f ? x + 1.f : __expf(x);   // elu(x)+1
}
// async global->LDS, 16B per lane; lds base must be wave-uniform
static __device__ __forceinline__ void gload16(const __bf16* g, __bf16* l) {
    __builtin_amdgcn_global_load_lds(
        (const __attribute__((address_space(1))) void*)g,
        (__attribute__((address_space(3))) void*)l, 16, 0, 0);
}

// ---------- workspace layout (bytes) ----------
#define OFF_QKV  0ull                              // float [4096][4096]   64 MB
#define OFF_SQ   67108864ull                       // bf16  (b,h,S,128)    16 MB  (pre-GEMM: hb)
#define OFF_QR   83886080ull                       // bf16  (b,h,S,128)    16 MB  (pre-GEMM: qkvT)
#define OFF_KR   100663296ull                      // bf16  (b,kvh,S,128)   8 MB
#define OFF_VT   109051904ull                      // bf16  (b,kvh,128,S)   8 MB
#define OFF_ND   117440512ull                      // float (b,h,S)       256 KB
#define OFF_CB   117702656ull                      // bf16  [4096][2048]   16 MB
#define OFF_PART 134479872ull                      // float 16*(...)  16 MB  (late: woT 8 MB)
#define NSPLIT 16

// =====================================================================
// K0a: fp32 -> bf16 bulk convert (8 elems/thread)
// =====================================================================
__global__ void f2b_k(const float* __restrict__ src, __bf16* __restrict__ dst)
{
    const size_t i = ((size_t)blockIdx.x * 256 + threadIdx.x) * 8;
    const float4 v0 = *reinterpret_cast<const float4*>(src + i);
    const float4 v1 = *reinterpret_cast<const float4*>(src + i + 4);
    bf16x8 t;
    t[0]=(__bf16)v0.x; t[1]=(__bf16)v0.y; t[2]=(__bf16)v0.z; t[3]=(__bf16)v0.w;
    t[4]=(__bf16)v1.x; t[5]=(__bf16)v1.y; t[6]=(__bf16)v1.z; t[7]=(__bf16)v1.w;
    *reinterpret_cast<bf16x8*>(dst + i) = t;
}

// =====================================================================
// K0b: W fp32 [K][N] -> Bt bf16 [N][K]  (64x64 LDS tile transpose)
// =====================================================================
__global__ __launch_bounds__(256) void tr_k(const float* __restrict__ W,
                                            __bf16* __restrict__ Bt, int K, int N)
{
    __shared__ __bf16 T[64][72];
    const int k0 = blockIdx.x * 64, n0 = blockIdx.y * 64;
    const int t = threadIdx.x;
    #pragma unroll
    for (int i = 0; i < 4; ++i) {
        const int idx = t + i * 256;           // 0..1023
        const int r = idx >> 4, c4 = (idx & 15) * 4;
        const float4 v = *reinterpret_cast<const float4*>(&W[(size_t)(k0 + r) * N + n0 + c4]);
        T[c4 + 0][r] = (__bf16)v.x; T[c4 + 1][r] = (__bf16)v.y;
        T[c4 + 2][r] = (__bf16)v.z; T[c4 + 3][r] = (__bf16)v.w;
    }
    __syncthreads();
    #pragma unroll
    for (int i = 0; i < 2; ++i) {
        const int idx = t + i * 256;           // 0..511
        const int rr = idx >> 3, cc = (idx & 7) * 8;
        *reinterpret_cast<bf16x8*>(&Bt[(size_t)(n0 + rr) * K + k0 + cc]) =
            *reinterpret_cast<bf16x8*>(&T[rr][cc]);
    }
}

// =====================================================================
// K1 / K8: m97-style GEMM. C[M][N] = A[M][K] @ Bt[N][K]^T, fp32 out.
// 128x128 tile, BK=32, global_load_lds width-16 staging.
// =====================================================================
__global__ __launch_bounds__(256) void gemm_bt(const __bf16* __restrict__ A,
                                               const __bf16* __restrict__ Bt,
                                               float* __restrict__ C,
                                               int N, int K)
{
    __shared__ __align__(16) __bf16 As[128 * 32];
    __shared__ __align__(16) __bf16 Bs[128 * 32];

    const int tid = threadIdx.x, wave = tid >> 6, lane = tid & 63;
    const int l15 = lane & 15, l4 = lane >> 4;
    const int m0 = blockIdx.x * 128, n0 = blockIdx.y * 128;
    const int wm = (wave & 1) * 64, wn = (wave >> 1) * 64;

    f32x4 acc[4][4] = {};

    // staging addresses: wave w issue i covers rows w*32+i*16 .. +16 of the tile
    const int srow = wave * 32 + (lane >> 2);
    const int scol = (lane & 3) * 8;
    const __bf16* Ab = A  + (size_t)(m0 + srow) * K + scol;
    const __bf16* Bb = Bt + (size_t)(n0 + srow) * K + scol;
    __bf16* AsB0 = &As[(wave * 32) * 32];
    __bf16* AsB1 = &As[(wave * 32 + 16) * 32];
    __bf16* BsB0 = &Bs[(wave * 32) * 32];
    __bf16* BsB1 = &Bs[(wave * 32 + 16) * 32];

    for (int kb = 0; kb < K; kb += 32) {
        gload16(Ab + kb,            AsB0);
        gload16(Ab + 16 * K + kb,   AsB1);
        gload16(Bb + kb,            BsB0);
        gload16(Bb + 16 * K + kb,   BsB1);
        __syncthreads();

        bf16x8 af[4], bfr[4];
        #pragma unroll
        for (int mt = 0; mt < 4; ++mt)
            af[mt] = *reinterpret_cast<bf16x8*>(&As[(wm + mt * 16 + l15) * 32 + l4 * 8]);
        #pragma unroll
        for (int nt = 0; nt < 4; ++nt)
            bfr[nt] = *reinterpret_cast<bf16x8*>(&Bs[(wn + nt * 16 + l15) * 32 + l4 * 8]);
        #pragma unroll
        for (int mt = 0; mt < 4; ++mt)
            #pragma unroll
            for (int nt = 0; nt < 4; ++nt)
                acc[mt][nt] = mfma16(af[mt], bfr[nt], acc[mt][nt]);
        __syncthreads();
    }

    #pragma unroll
    for (int mt = 0; mt < 4; ++mt)
        #pragma unroll
        for (int nt = 0; nt < 4; ++nt)
            #pragma unroll
            for (int r = 0; r < 4; ++r) {
                const int row = m0 + wm + mt * 16 + l4 * 4 + r;
                const int col = n0 + wn + nt * 16 + l15;
                C[(size_t)row * N + col] = acc[mt][nt][r];
            }
}

// =====================================================================
// K2: sigma_q, norm dots, RoPE(q,k), V^T  — one block per (b,h,s)
// qr is pre-scaled by 1/sqrt(HD).
// =====================================================================
__global__ void prep_k(const float* __restrict__ qkv, const float* __restrict__ norm_in,
                       const int* __restrict__ pos_ids,
                       __bf16* __restrict__ sq, __bf16* __restrict__ qr,
                       __bf16* __restrict__ kr, __bf16* __restrict__ vt,
                       float* __restrict__ nd)
{
    const int s = blockIdx.x, h = blockIdx.y, b = blockIdx.z, d = threadIdx.x;
    __shared__ float row[128];
    __shared__ float red[128];

    const float* qrow = qkv + (size_t)(b * SEQ + s) * QKV_N;
    float qv = qrow[h * 128 + d];
    float sqv = sigma_f(qv);
    sq[((size_t)(b * NH + h) * SEQ + s) * 128 + d] = (__bf16)sqv;

    red[d] = sqv * norm_in[(b * NKV + (h & 7)) * 128 + d];
    row[d] = qv;
    __syncthreads();
    for (int off = 64; off > 0; off >>= 1) {
        if (d < off) red[d] += red[d + off];
        __syncthreads();
    }
    if (d == 0) nd[(size_t)(b * NH + h) * SEQ + s] = red[0];

    // RoPE
    const int pos = pos_ids[s];
    const int j = d & 63;
    float inv = expf(-((float)(2 * j) / 128.f) * 9.210340371976184f); // ln(10000)
    float ang = (float)pos * inv;
    float c, sn;
    sincosf(ang, &sn, &c);
    float rot = (d < 64) ? -row[d + 64] : row[d - 64];
    const float scale = 0.08838834764831845f;   // 1/sqrt(128), folded into q
    qr[((size_t)(b * NH + h) * SEQ + s) * 128 + d] = (__bf16)((qv * c + rot * sn) * scale);

    if (h < NKV) {
        float kv = qrow[2048 + h * 128 + d];
        float vv = qrow[3072 + h * 128 + d];
        __syncthreads();
        row[d] = kv;
        __syncthreads();
        float rotk = (d < 64) ? -row[d + 64] : row[d - 64];
        kr[((size_t)(b * NKV + h) * SEQ + s) * 128 + d] = (__bf16)(kv * c + rotk * sn);
        vt[((size_t)((b * NKV + h) * 128 + d)) * SEQ + s] = (__bf16)vv;
    }
}

// =====================================================================
// K3: memory_output = (sigma_q @ mem) / nd, write g*val into combined
// =====================================================================
__global__ __launch_bounds__(256) void memout_k(const __bf16* __restrict__ sq,
                                                const float* __restrict__ mem_in,
                                                const float* __restrict__ nd,
                                                const float* __restrict__ gate,
                                                __bf16* __restrict__ cb)
{
    __shared__ __align__(16) __bf16 mt[128][136];   // mem^T [e][d]
    const int tid = threadIdx.x;
    const int h = blockIdx.y, b = blockIdx.z;
    const int s0 = blockIdx.x * 64;

    const float* mem = mem_in + (size_t)(b * NKV + (h & 7)) * 16384;
    for (int i = tid; i < 16384; i += 256) {
        int dd = i >> 7, e = i & 127;
        mt[e][dd] = (__bf16)mem[i];
    }
    __syncthreads();

    const int wave = tid >> 6, lane = tid & 63, l15 = lane & 15, l4 = lane >> 4;
    f32x4 acc[8] = {};
    const __bf16* sqb = sq + ((size_t)(b * NH + h) * SEQ + s0 + wave * 16 + l15) * 128;
    #pragma unroll
    for (int kb = 0; kb < 4; ++kb) {
        bf16x8 a = *reinterpret_cast<const bf16x8*>(sqb + kb * 32 + l4 * 8);
        #pragma unroll
        for (int nc = 0; nc < 8; ++nc) {
            bf16x8 bb = *reinterpret_cast<bf16x8*>(&mt[nc * 16 + l15][kb * 32 + l4 * 8]);
            acc[nc] = mfma16(a, bb, acc[nc]);
        }
    }
    float g = 1.f / (1.f + __expf(-gate[h]));
    #pragma unroll
    for (int r = 0; r < 4; ++r) {
        int srow = s0 + wave * 16 + l4 * 4 + r;
        float scl = g / nd[(size_t)(b * NH + h) * SEQ + srow];
        __bf16* cbp = cb + (size_t)(b * SEQ + srow) * HID + h * 128;
        #pragma unroll
        for (int nc = 0; nc < 8; ++nc)
            cbp[nc * 16 + l15] = (__bf16)(acc[nc][r] * scl);
    }
}

// =====================================================================
// K4: updated_norm = norm_in + sum_s sigma_k
// =====================================================================
__global__ void normupd_k(const float* __restrict__ qkv, const float* __restrict__ norm_in,
                          float* __restrict__ out_norm)
{
    const int h = blockIdx.x, b = blockIdx.y;
    const int t = threadIdx.x, d = t & 127, sg = t >> 7;   // 512 threads: 4 s-groups
    __shared__ float pr[4][128];
    float acc = 0.f;
    for (int s = sg; s < SEQ; s += 4) {
        float kv = qkv[(size_t)(b * SEQ + s) * QKV_N + 2048 + h * 128 + d];
        acc += sigma_f(kv);
    }
    pr[sg][d] = acc;
    __syncthreads();
    if (sg == 0)
        out_norm[(b * NKV + h) * 128 + d] =
            norm_in[(b * NKV + h) * 128 + d] + pr[0][d] + pr[1][d] + pr[2][d] + pr[3][d];
}

// =====================================================================
// K5: updated_memory partials: part[sp] = sigma_k^T @ v over s-chunk
// =====================================================================
__global__ __launch_bounds__(256) void memupd_k(const float* __restrict__ qkv,
                                                float* __restrict__ part)
{
    const int sp = blockIdx.x, h = blockIdx.y, b = blockIdx.z;
    const int tid = threadIdx.x;
    const int tx = tid & 15, ty = tid >> 4;   // d-block tx*8, e-block ty*8
    __shared__ __align__(16) float sk[8][128];
    __shared__ __align__(16) float sv[8][128];
    float acc[8][8] = {};

    const int s0 = sp * (SEQ / NSPLIT);
    for (int so = 0; so < SEQ / NSPLIT; so += 8) {
        for (int i = tid; i < 8 * 128; i += 256) {
            int rr = i >> 7, dd = i & 127;
            const float* rowp = qkv + (size_t)(b * SEQ + s0 + so + rr) * QKV_N;
            sk[rr][dd] = sigma_f(rowp[2048 + h * 128 + dd]);
            sv[rr][dd] = rowp[3072 + h * 128 + dd];
        }
        __syncthreads();
        #pragma unroll
        for (int rr = 0; rr < 8; ++rr) {
            float4 k0 = *reinterpret_cast<float4*>(&sk[rr][tx * 8]);
            float4 k1 = *reinterpret_cast<float4*>(&sk[rr][tx * 8 + 4]);
            float4 v0 = *reinterpret_cast<float4*>(&sv[rr][ty * 8]);
            float4 v1 = *reinterpret_cast<float4*>(&sv[rr][ty * 8 + 4]);
            float kreg[8] = {k0.x,k0.y,k0.z,k0.w,k1.x,k1.y,k1.z,k1.w};
            float vreg[8] = {v0.x,v0.y,v0.z,v0.w,v1.x,v1.y,v1.z,v1.w};
            #pragma unroll
            for (int i = 0; i < 8; ++i)
                #pragma unroll
                for (int j2 = 0; j2 < 8; ++j2)
                    acc[i][j2] += kreg[i] * vreg[j2];
        }
        __syncthreads();
    }
    float* pb = part + ((size_t)sp * (BATCH * NKV) + b * NKV + h) * 16384;
    #pragma unroll
    for (int i = 0; i < 8; ++i)
        #pragma unroll
        for (int j2 = 0; j2 < 8; ++j2)
            pb[(tx * 8 + i) * 128 + ty * 8 + j2] = acc[i][j2];
}

// K6: reduce partials + memory_in
__global__ void memred_k(const float* __restrict__ part, const float* __restrict__ mem_in,
                         float* __restrict__ out_mem)
{
    const size_t i = (size_t)blockIdx.x * 256 + threadIdx.x;   // 262144 total
    float a = mem_in[i];
    #pragma unroll
    for (int sp = 0; sp < NSPLIT; ++sp) a += part[(size_t)sp * 262144 + i];
    out_mem[i] = a;
}

// =====================================================================
// K7: flash causal attention (balanced q-tile pairs + LDS staging).
// =====================================================================
__global__ __launch_bounds__(256) void attn_k(const __bf16* __restrict__ qr,
                                              const __bf16* __restrict__ kr,
                                              const __bf16* __restrict__ vt,
                                              const float* __restrict__ gate,
                                              __bf16* __restrict__ cb)
{
    __shared__ __align__(16) __bf16 Ks[64][136];    // [key][d]   (+8 pad)
    __shared__ __align__(16) __bf16 Vs[128][72];    // [d][key]   (+8 pad)
    __shared__ __align__(16) __bf16 plds[4][16][72];// per-wave P transpose

    const int tid = threadIdx.x, wave = tid >> 6, lane = tid & 63;
    const int l15 = lane & 15, l4 = lane >> 4;
    const int h = blockIdx.y, b = blockIdx.z;
    const int kvh = h >> 1;

    const __bf16* kbase = kr + (size_t)(b * NKV + kvh) * SEQ * 128;
    const __bf16* vbase = vt + (size_t)(b * NKV + kvh) * 128 * SEQ;

    const float g  = 1.f / (1.f + __expf(-gate[h]));
    const float gi = 1.f - g;

    const int k_row = tid >> 4, k_col = (tid & 15) * 8;   // K: 16 rows/round
    const int v_row = tid >> 3, v_col = (tid & 7) * 8;    // V: 32 rows/round

    #pragma unroll 1
    for (int tile = 0; tile < 2; ++tile) {
        const int q0 = (tile == 0 ? blockIdx.x : 31 - blockIdx.x) * 64;
        const int qw = q0 + wave * 16;

        const __bf16* qbase = qr + ((size_t)(b * NH + h) * SEQ + qw + l15) * 128;
        bf16x8 af[4];
        #pragma unroll
        for (int kb = 0; kb < 4; ++kb)
            af[kb] = *reinterpret_cast<const bf16x8*>(qbase + kb * 32 + l4 * 8);

        f32x4 o[8] = {};
        float mi[4] = {-1e30f, -1e30f, -1e30f, -1e30f};
        float li[4] = {0.f, 0.f, 0.f, 0.f};

        #pragma unroll 1
        for (int kt = 0; kt < q0 + 64; kt += 64) {
            #pragma unroll
            for (int r = 0; r < 4; ++r) {
                *reinterpret_cast<bf16x8*>(&Ks[r * 16 + k_row][k_col]) =
                    *reinterpret_cast<const bf16x8*>(kbase + (size_t)(kt + r * 16 + k_row) * 128 + k_col);
            }
            #pragma unroll
            for (int r = 0; r < 4; ++r) {
                *reinterpret_cast<bf16x8*>(&Vs[r * 32 + v_row][v_col]) =
                    *reinterpret_cast<const bf16x8*>(vbase + (size_t)(r * 32 + v_row) * SEQ + kt + v_col);
            }
            __syncthreads();

            f32x4 sv[4] = {};
            #pragma unroll
            for (int kb = 0; kb < 4; ++kb) {
                #pragma unroll
                for (int sub = 0; sub < 4; ++sub) {
                    bf16x8 bb = *reinterpret_cast<bf16x8*>(&Ks[sub * 16 + l15][kb * 32 + l4 * 8]);
                    sv[sub] = mfma16(af[kb], bb, sv[sub]);
                }
            }

            #pragma unroll
            for (int r = 0; r < 4; ++r) {
                const int qrow = qw + l4 * 4 + r;
                float p[4];
                float mx = -1e30f;
                #pragma unroll
                for (int sub = 0; sub < 4; ++sub) {
                    int key = kt + sub * 16 + l15;
                    p[sub] = (key <= qrow) ? sv[sub][r] : -1e30f;
                    mx = fmaxf(mx, p[sub]);
                }
                #pragma unroll
                for (int msk = 1; msk < 16; msk <<= 1) mx = fmaxf(mx, __shfl_xor(mx, msk));
                const float mnew = fmaxf(mi[r], mx);
                const float alpha = __expf(mi[r] - mnew);
                float rs = 0.f;
                #pragma unroll
                for (int sub = 0; sub < 4; ++sub) {
                    p[sub] = __expf(p[sub] - mnew);
                    rs += p[sub];
                    plds[wave][l4 * 4 + r][sub * 16 + l15] = (__bf16)p[sub];
                }
                #pragma unroll
                for (int msk = 1; msk < 16; msk <<= 1) rs += __shfl_xor(rs, msk);
                li[r] = li[r] * alpha + rs;
                mi[r] = mnew;
                #pragma unroll
                for (int nc = 0; nc < 8; ++nc) o[nc][r] *= alpha;
            }

            bf16x8 ap0 = *reinterpret_cast<bf16x8*>(&plds[wave][l15][l4 * 8]);
            bf16x8 ap1 = *reinterpret_cast<bf16x8*>(&plds[wave][l15][32 + l4 * 8]);
            #pragma unroll
            for (int nc = 0; nc < 8; ++nc) {
                bf16x8 b0 = *reinterpret_cast<bf16x8*>(&Vs[nc * 16 + l15][l4 * 8]);
                bf16x8 b1 = *reinterpret_cast<bf16x8*>(&Vs[nc * 16 + l15][32 + l4 * 8]);
                o[nc] = mfma16(ap0, b0, o[nc]);
                o[nc] = mfma16(ap1, b1, o[nc]);
            }
            __syncthreads();
        }

        #pragma unroll
        for (int r = 0; r < 4; ++r) {
            const int qrow = qw + l4 * 4 + r;
            const float inv = gi / li[r];
            __bf16* cbp = cb + (size_t)(b * SEQ + qrow) * HID + h * 128;
            #pragma unroll
            for (int nc = 0; nc < 8; ++nc) {
                const int dd = nc * 16 + l15;
                float prev = (float)cbp[dd];
                cbp[dd] = (__bf16)(prev + o[nc][r] * inv);
            }
        }
    }
}

// =====================================================================
extern "C" void kernel_launch(void* const* d_in, const int* in_sizes, int n_in,
                              void* d_out, int out_size, void* d_ws, size_t ws_size,
                              hipStream_t stream)
{
    const float* hidden  = (const float*)d_in[0];
    const float* Wq      = (const float*)d_in[1];
    const float* Wk      = (const float*)d_in[2];
    const float* Wv      = (const float*)d_in[3];
    const float* Wo      = (const float*)d_in[4];
    const float* gate    = (const float*)d_in[5];
    const float* mem_in  = (const float*)d_in[6];
    const float* norm_in = (const float*)d_in[7];
    const int*   pos     = (const int*)d_in[8];

    float* out_final = (float*)d_out;                  // (B,S,HID)
    float* out_mem   = out_final + (size_t)BATCH * SEQ * HID;     // (B,8,128,128)
    float* out_norm  = out_mem + (size_t)BATCH * NKV * 128 * 128; // (B,8,1,128)

    char* ws = (char*)d_ws;
    float*  qkv  = (float*)(ws + OFF_QKV);
    __bf16* sq   = (__bf16*)(ws + OFF_SQ);
    __bf16* qrb  = (__bf16*)(ws + OFF_QR);
    __bf16* krb  = (__bf16*)(ws + OFF_KR);
    __bf16* vtb  = (__bf16*)(ws + OFF_VT);
    float*  nd   = (float*)(ws + OFF_ND);
    __bf16* cb   = (__bf16*)(ws + OFF_CB);
    float*  part = (float*)(ws + OFF_PART);
    // overlays (lifetimes disjoint from the named owners):
    __bf16* hb   = (__bf16*)(ws + OFF_SQ);    // bf16 hidden  [4096][2048], dead after gemm1
    __bf16* qkvT = (__bf16*)(ws + OFF_QR);    // bf16 W_qkv^T [4096][2048], dead after gemm1
    __bf16* woT  = (__bf16*)(ws + OFF_PART);  // bf16 Wo^T    [2048][2048], after memred

    // 0. bf16 conversions / weight transposes
    f2b_k<<<(M_ROWS * HID) / (256 * 8), 256, 0, stream>>>(hidden, hb);
    tr_k<<<dim3(HID / 64, 2048 / 64), 256, 0, stream>>>(Wq, qkvT, HID, 2048);
    tr_k<<<dim3(HID / 64, 1024 / 64), 256, 0, stream>>>(Wk, qkvT + (size_t)2048 * HID, HID, 1024);
    tr_k<<<dim3(HID / 64, 1024 / 64), 256, 0, stream>>>(Wv, qkvT + (size_t)3072 * HID, HID, 1024);

    // 1. fused QKV projection: [4096 x 2048] @ [2048 x 4096]
    gemm_bt<<<dim3(M_ROWS / 128, QKV_N / 128), 256, 0, stream>>>(hb, qkvT, qkv, QKV_N, HID);

    // 2. sigma_q / norm-dot / RoPE / V^T  (overwrites hb/qkvT regions — now dead)
    prep_k<<<dim3(SEQ, NH, BATCH), 128, 0, stream>>>(qkv, norm_in, pos, sq, qrb, krb, vtb, nd);

    // 3. memory_output -> combined (g * memout / nd)
    memout_k<<<dim3(SEQ / 64, NH, BATCH), 256, 0, stream>>>(sq, mem_in, nd, gate, cb);

    // 4. updated_norm
    normupd_k<<<dim3(NKV, BATCH), 512, 0, stream>>>(qkv, norm_in, out_norm);

    // 5/6. updated_memory
    memupd_k<<<dim3(NSPLIT, NKV, BATCH), 256, 0, stream>>>(qkv, part);
    memred_k<<<(BATCH * NKV * 128 * 128) / 256, 256, 0, stream>>>(part, mem_in, out_mem);

    // 6b. Wo^T (overlays part — dead after memred)
    tr_k<<<dim3(HID / 64, HID / 64), 256, 0, stream>>>(Wo, woT, HID, HID);

    // 7. causal attention (balanced q-tile pairs), adds (1-g)*attn into combined
    attn_k<<<dim3(16, NH, BATCH), 256, 0, stream>>>(qrb, krb, vtb, gate, cb);

    // 8. output projection: [4096 x 2048] @ [2048 x 2048]
    gemm_bt<<<dim3(M_ROWS / 128, HID / 128), 256, 0, stream>>>(cb, woT, out_final, HID, HID);
}